// Round 12
// baseline (112.387 us; speedup 1.0000x reference)
//
#include <hip/hip_runtime.h>
#include <cmath>

#define N_NODES 10000
#define UNITS   64
#define IND     2
#define BATCH   16
#define NEDGE   80000
#define FDIM    66            // IND + UNITS
#define OG      128           // 2*UNITS
#define OC      64            // UNITS
#define HXS     (N_NODES*UNITS)
#define INS     (N_NODES*IND)
#define KTILES  5             // ceil(132/32)
#define FQ      17            // f-quads per row (F padded 66->68)
#define CHUNKS  272           // 16*17 quads per row
#define LDSC    21            // padded fq stride in LDS
#define CAP     64            // bucket capacity per node (mean deg 8)
#define SCH     34            // chunks per XCD slice (272/8)
#define NPB     7             // nodes per spmm block (7*34 = 238 <= 256)

typedef __attribute__((ext_vector_type(8))) short bf16x8;
typedef __attribute__((ext_vector_type(4))) float f32x4;
typedef __attribute__((ext_vector_type(2))) float f32x2;
typedef unsigned long long u64;

__device__ __forceinline__ float bf2f(unsigned short u) {
  union { unsigned u; float f; } v; v.u = ((unsigned)u) << 16; return v.f;
}
__device__ __forceinline__ unsigned short f2bf(float x) {
  union { float f; unsigned u; } v; v.f = x;
  unsigned r = v.u + 0x7fffu + ((v.u >> 16) & 1u);
  return (unsigned short)(r >> 16);
}
__device__ __forceinline__ unsigned cvt2bf(float a, float b) {   // lo=bf16(a), hi=bf16(b)
  unsigned r; asm("v_cvt_pk_bf16_f32 %0, %1, %2" : "=v"(r) : "v"(a), "v"(b)); return r;
}
__device__ __forceinline__ unsigned pk4fp8(float a, float b, float c, float d) {
  int v = __builtin_amdgcn_cvt_pk_fp8_f32(a, b, 0, false);
  v = __builtin_amdgcn_cvt_pk_fp8_f32(c, d, v, true);
  return (unsigned)v;
}
__device__ __forceinline__ unsigned char f2fp8(float a) {
  return (unsigned char)(__builtin_amdgcn_cvt_pk_fp8_f32(a, 0.f, 0, false) & 0xff);
}

// ================= fused prep: pack W | fill buckets | build X8 + X0bf =================
__global__ __launch_bounds__(256) void prep_kernel(
    const float* __restrict__ inputs, const float* __restrict__ hx,
    const float* __restrict__ w1mu, const float* __restrict__ w1ls, const float* __restrict__ ew1,
    const float* __restrict__ b1mu, const float* __restrict__ b1ls, const float* __restrict__ eb1,
    const float* __restrict__ w2mu, const float* __restrict__ w2ls, const float* __restrict__ ew2,
    const float* __restrict__ b2mu, const float* __restrict__ b2ls, const float* __restrict__ eb2,
    const int* __restrict__ erow, const int* __restrict__ ecol, const float* __restrict__ eval,
    short* __restrict__ W1p, short* __restrict__ W2p,
    float* __restrict__ B1, float* __restrict__ B2,
    int* __restrict__ cnt, u64* __restrict__ epk,
    unsigned* __restrict__ X8, uint2* __restrict__ X0bf) {
  int blk = blockIdx.x, t = threadIdx.x;
  if (blk < 16) {                    // ---- pack W (fused reparam) ----
    int i = blk * 256 + t;
    if (i < 2560) {
      int l = i & 63, kt = (i >> 6) % KTILES, nt = i / (KTILES * 64);
      int o = nt * 16 + (l & 15), s = l >> 4;
      bf16x8 fr;
#pragma unroll
      for (int j = 0; j < 8; ++j) {
        int f = kt * 16 + s * 4 + (j & 3);
        int src = j >> 2;
        float w = 0.f;
        if (f < FDIM) { int idx = (2 * f + src) * OG + o; w = w1mu[idx] + __expf(w1ls[idx]) * ew1[idx]; }
        fr[j] = (short)f2bf(w);
      }
      *((bf16x8*)W1p + i) = fr;
    } else if (i < 3840) {
      int i2 = i - 2560;
      int l = i2 & 63, kt = (i2 >> 6) % KTILES, nt = i2 / (KTILES * 64);
      int o = nt * 16 + (l & 15), s = l >> 4;
      bf16x8 fr;
#pragma unroll
      for (int j = 0; j < 8; ++j) {
        int f = kt * 16 + s * 4 + (j & 3);
        int src = j >> 2;
        float w = 0.f;
        if (f < FDIM) { int idx = (2 * f + src) * OC + o; w = w2mu[idx] + __expf(w2ls[idx]) * ew2[idx]; }
        fr[j] = (short)f2bf(w);
      }
      *((bf16x8*)W2p + i2) = fr;
    } else if (i < 3968) {
      int j = i - 3840; B1[j] = b1mu[j] + __expf(b1ls[j]) * eb1[j];
    } else if (i < 4032) {
      int j = i - 3968; B2[j] = b2mu[j] + __expf(b2ls[j]) * eb2[j];
    }
  } else if (blk < 16 + 313) {       // ---- fill buckets ----
    int i = (blk - 16) * 256 + t;
    if (i < NEDGE) {
      int r = erow[i];
      int pos = atomicAdd(&cnt[r], 1);
      if (pos < CAP)
        epk[(size_t)r * CAP + pos] =
            (u64)(unsigned)(ecol[i] * CHUNKS) | ((u64)__float_as_uint(eval[i]) << 32);
    }
  } else {                           // ---- build X8 (fp8) + X0bf (bf16) ----
    int i = (blk - 329) * 256 + t;
    if (i >= N_NODES * CHUNKS) return;
    int n = i / CHUNKS;
    int c = i - n * CHUNKS;
    int b = c / FQ;
    int fq = c - b * FQ;
    const float* hp = hx + (size_t)b * HXS + n * UNITS;
    float v0, v1, v2, v3;
    if (fq == 0) {
      const float* ip = inputs + (size_t)b * INS + n * IND;
      v0 = ip[0]; v1 = ip[1]; v2 = hp[0]; v3 = hp[1];
    } else if (fq < 16) {
      f32x2 a = *reinterpret_cast<const f32x2*>(hp + fq * 4 - 2);
      f32x2 d = *reinterpret_cast<const f32x2*>(hp + fq * 4);
      v0 = a[0]; v1 = a[1]; v2 = d[0]; v3 = d[1];
    } else {
      f32x2 a = *reinterpret_cast<const f32x2*>(hp + 62);
      v0 = a[0]; v1 = a[1]; v2 = 0.f; v3 = 0.f;
    }
    X8[i] = pk4fp8(v0, v1, v2, v3);
    X0bf[i] = make_uint2(cvt2bf(v0, v1), cvt2bf(v2, v3));
  }
}

// ========== XCD-sliced SpMM: x1 = A @ X8 -> X1 (bf16) ==========
// slice s = blockIdx % 8 -> XCD s (round-robin dispatch); its 1.36 MB table
// slice stays L2-resident on that XCD. Each block: NPB nodes x SCH chunks.
__global__ __launch_bounds__(256) void spmm_kernel(
    const unsigned* __restrict__ X8t, const int* __restrict__ cnt,
    const u64* __restrict__ epk, uint2* __restrict__ X1) {
  int bid = blockIdx.x, t = threadIdx.x;
  int s = bid & 7, g = bid >> 3;
  int nl = t / SCH, ch = t - nl * SCH;
  int n = g * NPB + nl;
  if (nl >= NPB || n >= N_NODES) return;
  int c = s * SCH + ch;
  int deg = cnt[n]; if (deg > CAP) deg = CAP;
  const u64* ebk = epk + (size_t)n * CAP;
  const unsigned* bc = X8t + c;
  f32x2 g01 = {0.f, 0.f}, g23 = {0.f, 0.f};
  // masked 8-edge head (buckets always readable; masked edges add exact 0)
  {
    unsigned o[8]; float v[8];
#pragma unroll
    for (int j = 0; j < 8; ++j) {
      u64 p = ebk[j];
      bool on = j < deg;
      o[j] = on ? (unsigned)p : 0u;
      v[j] = on ? __uint_as_float((unsigned)(p >> 32)) : 0.f;
    }
    unsigned wv[8];
#pragma unroll
    for (int j = 0; j < 8; ++j) wv[j] = bc[o[j]];
#pragma unroll
    for (int j = 0; j < 8; ++j) {
      f32x2 vv = {v[j], v[j]};
      g01 += vv * __builtin_amdgcn_cvt_pk_f32_fp8((int)wv[j], false);
      g23 += vv * __builtin_amdgcn_cvt_pk_f32_fp8((int)wv[j], true);
    }
  }
  for (int e = 8; e < deg; e += 4) {
    unsigned o[4]; float v[4];
#pragma unroll
    for (int j = 0; j < 4; ++j) {
      int ee = e + j;
      u64 p = ebk[ee < CAP ? ee : CAP - 1];
      bool on = ee < deg;
      o[j] = on ? (unsigned)p : 0u;
      v[j] = on ? __uint_as_float((unsigned)(p >> 32)) : 0.f;
    }
    unsigned wv[4];
#pragma unroll
    for (int j = 0; j < 4; ++j) wv[j] = bc[o[j]];
#pragma unroll
    for (int j = 0; j < 4; ++j) {
      f32x2 vv = {v[j], v[j]};
      g01 += vv * __builtin_amdgcn_cvt_pk_f32_fp8((int)wv[j], false);
      g23 += vv * __builtin_amdgcn_cvt_pk_f32_fp8((int)wv[j], true);
    }
  }
  X1[(size_t)n * CHUNKS + c] = make_uint2(cvt2bf(g01[0], g01[1]), cvt2bf(g23[0], g23[1]));
}

// A-frag: lane (ml,s) kt reads 16B = (x0[f0..f0+3], x1[f0..f0+3]), f0 = kt*16+s*4
__device__ __forceinline__ void build_afrag(const unsigned short* Y, int ml, int s, bf16x8* af) {
#pragma unroll
  for (int kt = 0; kt < KTILES; ++kt)
    af[kt] = *reinterpret_cast<const bf16x8*>(Y + (ml * LDSC + kt * 4 + s) * 8);
}

// ------- gates: streaming Y build (X0bf + X1) + MFMA + sigmoid;
//         r*h -> X8c (fp8, LDS-staged), {u,u*h} -> upk. -------
__global__ __launch_bounds__(256) void gates_kernel(
    const uint2* __restrict__ X0bf, const uint2* __restrict__ X1,
    const short* __restrict__ W1p, const float* __restrict__ B1,
    unsigned* __restrict__ X8c, unsigned* __restrict__ upk) {
  __shared__ __align__(16) unsigned short Y[16 * LDSC * 8];
  __shared__ __align__(16) unsigned X8s[CHUNKS];
  int n = blockIdx.x, t = threadIdx.x;
  int lane = t & 63, w = t >> 6;

  const uint2* xrow = X0bf + (size_t)n * CHUNKS;
  const uint2* x1row = X1 + (size_t)n * CHUNKS;
  uint2 own = xrow[t];
  uint2 g1 = x1row[t];
  int b0 = t / FQ, fq0 = t - b0 * FQ;
  X8s[t] = (fq0 == 0)
      ? pk4fp8(bf2f((unsigned short)(own.x & 0xffffu)), bf2f((unsigned short)(own.x >> 16)), 0.f, 0.f)
      : 0u;
  if (t < 48) {                       // zero LDS pads fq' 17..19
    int b = t / 3, fqp = 17 + (t - (t / 3) * 3);
    *reinterpret_cast<uint4*>(Y + (b * LDSC + fqp) * 8) = make_uint4(0u, 0u, 0u, 0u);
  }
  *reinterpret_cast<uint4*>(Y + ((t / FQ) * LDSC + fq0) * 8) =
      make_uint4(own.x, own.y, g1.x, g1.y);
  if (t < 16) {                       // extra chunk c2 = 256+t -> b=15, fq = t+1
    uint2 own2 = xrow[256 + t];
    uint2 g1e = x1row[256 + t];
    *reinterpret_cast<uint4*>(Y + (15 * LDSC + (t + 1)) * 8) =
        make_uint4(own2.x, own2.y, g1e.x, g1e.y);
    X8s[256 + t] = 0u;
  }
  __syncthreads();                   // Y + X8s init complete

  int ml = lane & 15, s = lane >> 4;
  bf16x8 af[KTILES];
  build_afrag(Y, ml, s, af);

  const bf16x8* Wp = (const bf16x8*)W1p;
#pragma unroll
  for (int q = 0; q < 2; ++q) {
    int nt = w * 2 + q;
    f32x4 acc = {0.f, 0.f, 0.f, 0.f};
#pragma unroll
    for (int kt = 0; kt < KTILES; ++kt)
      acc = __builtin_amdgcn_mfma_f32_16x16x32_bf16(af[kt], Wp[(nt * KTILES + kt) * 64 + lane],
                                                    acc, 0, 0, 0);
    int o = nt * 16 + ml;           // output col; rows = batch s*4+r
    float bias = B1[o];
    int f = (o < UNITS ? o : o - UNITS) + IND, fqi = f >> 2, fr = f & 3;
    if (o < UNITS) {
#pragma unroll
      for (int r = 0; r < 4; ++r) {
        int b = s * 4 + r;
        float h = bf2f(Y[(b * LDSC + fqi) * 8 + fr]);   // h (bf16) from staged own-row x0 quad
        float sg = 1.f / (1.f + __expf(-(acc[r] + bias)));
        ((unsigned char*)X8s)[(b * FQ + fqi) * 4 + fr] = f2fp8(sg * h);
      }
    } else {
      int ou = o - UNITS;
#pragma unroll
      for (int r = 0; r < 4; ++r) {
        int b = s * 4 + r;
        float h = bf2f(Y[(b * LDSC + fqi) * 8 + fr]);
        float u = 1.f / (1.f + __expf(-(acc[r] + bias)));
        upk[(size_t)b * HXS + n * UNITS + ou] = cvt2bf(u, u * h);
      }
    }
  }
  __syncthreads();                   // X8s bytes complete
  X8c[(size_t)n * CHUNKS + t] = X8s[t];
  if (t < 16) X8c[(size_t)n * CHUNKS + 256 + t] = X8s[256 + t];
}

// ------- candidate: streaming Y build (X8c own + X1) + MFMA + tanh + GRU combine -------
__global__ __launch_bounds__(256) void cand_kernel(
    const unsigned* __restrict__ X8c, const uint2* __restrict__ X1,
    const short* __restrict__ W2p, const float* __restrict__ B2,
    const unsigned* __restrict__ upk, float* __restrict__ out) {
  __shared__ __align__(16) unsigned short Y[16 * LDSC * 8];
  int n = blockIdx.x, t = threadIdx.x;
  int lane = t & 63, w = t >> 6;

  const unsigned* xrow = X8c + (size_t)n * CHUNKS;
  const uint2* x1row = X1 + (size_t)n * CHUNKS;
  unsigned wo = xrow[t];
  uint2 g1 = x1row[t];
  f32x2 lo = __builtin_amdgcn_cvt_pk_f32_fp8((int)wo, false);
  f32x2 hi = __builtin_amdgcn_cvt_pk_f32_fp8((int)wo, true);
  if (t < 48) {
    int b = t / 3, fqp = 17 + (t - (t / 3) * 3);
    *reinterpret_cast<uint4*>(Y + (b * LDSC + fqp) * 8) = make_uint4(0u, 0u, 0u, 0u);
  }
  int b0 = t / FQ, fq0 = t - b0 * FQ;
  *reinterpret_cast<uint4*>(Y + (b0 * LDSC + fq0) * 8) =
      make_uint4(cvt2bf(lo[0], lo[1]), cvt2bf(hi[0], hi[1]), g1.x, g1.y);
  if (t < 16) {
    unsigned wo2 = xrow[256 + t];
    uint2 g1e = x1row[256 + t];
    f32x2 lo2 = __builtin_amdgcn_cvt_pk_f32_fp8((int)wo2, false);
    f32x2 hi2 = __builtin_amdgcn_cvt_pk_f32_fp8((int)wo2, true);
    *reinterpret_cast<uint4*>(Y + (15 * LDSC + (t + 1)) * 8) =
        make_uint4(cvt2bf(lo2[0], lo2[1]), cvt2bf(hi2[0], hi2[1]), g1e.x, g1e.y);
  }
  __syncthreads();

  int ml = lane & 15, s = lane >> 4;
  bf16x8 af[KTILES];
  build_afrag(Y, ml, s, af);

  const bf16x8* Wp = (const bf16x8*)W2p;
  f32x4 acc = {0.f, 0.f, 0.f, 0.f};
#pragma unroll
  for (int kt = 0; kt < KTILES; ++kt)
    acc = __builtin_amdgcn_mfma_f32_16x16x32_bf16(af[kt], Wp[(w * KTILES + kt) * 64 + lane],
                                                  acc, 0, 0, 0);
  int o = w * 16 + ml;
  float bias = B2[o];
#pragma unroll
  for (int r = 0; r < 4; ++r) {
    int b = s * 4 + r;
    size_t idx = (size_t)b * HXS + n * UNITS + o;
    float x = acc[r] + bias;
    float c = 1.f - 2.f / (__expf(2.f * x) + 1.f);   // tanh
    unsigned pk = upk[idx];
    float u = bf2f((unsigned short)(pk & 0xffffu));
    float uh = bf2f((unsigned short)(pk >> 16));
    out[idx] = uh + (1.f - u) * c;
  }
}

extern "C" void kernel_launch(void* const* d_in, const int* in_sizes, int n_in,
                              void* d_out, int out_size, void* d_ws, size_t ws_size,
                              hipStream_t stream) {
  const float* inputs = (const float*)d_in[0];
  const float* hx     = (const float*)d_in[1];
  const float* eval   = (const float*)d_in[2];
  const float* w1mu   = (const float*)d_in[3];
  const float* w1ls   = (const float*)d_in[4];
  const float* b1mu   = (const float*)d_in[5];
  const float* b1ls   = (const float*)d_in[6];
  const float* w2mu   = (const float*)d_in[7];
  const float* w2ls   = (const float*)d_in[8];
  const float* b2mu   = (const float*)d_in[9];
  const float* b2ls   = (const float*)d_in[10];
  const float* ew1    = (const float*)d_in[11];
  const float* eb1    = (const float*)d_in[12];
  const float* ew2    = (const float*)d_in[13];
  const float* eb2    = (const float*)d_in[14];
  const int* erow     = (const int*)d_in[15];
  const int* ecol     = (const int*)d_in[16];
  float* out = (float*)d_out;

  char* p = (char*)d_ws;
  short* W1p = (short*)p;                   p += 20480 * 2;
  short* W2p = (short*)p;                   p += 10240 * 2;
  float* B1  = (float*)p;                   p += 128 * 4;
  float* B2  = (float*)p;                   p += 64 * 4;
  unsigned* X8  = (unsigned*)p;             p += (size_t)N_NODES * CHUNKS * 4;
  unsigned* X8c = (unsigned*)p;             p += (size_t)N_NODES * CHUNKS * 4;
  uint2* X0bf = (uint2*)p;                  p += (size_t)N_NODES * CHUNKS * 8;
  uint2* X1   = (uint2*)p;                  p += (size_t)N_NODES * CHUNKS * 8;
  unsigned* upk = (unsigned*)p;             p += (size_t)BATCH * HXS * 4;
  int* cnt    = (int*)p;                    p += N_NODES * 4;
  u64* epk    = (u64*)p;                    p += (size_t)N_NODES * CAP * 8;

  int spmm_grid = 8 * ((N_NODES + NPB - 1) / NPB);
  hipMemsetAsync(cnt, 0, N_NODES * sizeof(int), stream);
  prep_kernel<<<16 + 313 + (N_NODES * CHUNKS) / 256, 256, 0, stream>>>(
      inputs, hx, w1mu, w1ls, ew1, b1mu, b1ls, eb1,
      w2mu, w2ls, ew2, b2mu, b2ls, eb2, erow, ecol, eval,
      W1p, W2p, B1, B2, cnt, epk, X8, X0bf);
  spmm_kernel<<<spmm_grid, 256, 0, stream>>>(X8, cnt, epk, X1);
  gates_kernel<<<N_NODES, 256, 0, stream>>>(X0bf, X1, W1p, B1, X8c, upk);
  spmm_kernel<<<spmm_grid, 256, 0, stream>>>(X8c, cnt, epk, X1);
  cand_kernel<<<N_NODES, 256, 0, stream>>>(X8c, X1, W2p, B2, upk, out);
}

// Round 13
// 90.425 us; speedup vs baseline: 1.2429x; 1.2429x over previous
//
#include <hip/hip_runtime.h>
#include <cmath>

#define N_NODES 10000
#define UNITS   64
#define IND     2
#define BATCH   16
#define NEDGE   80000
#define FDIM    66            // IND + UNITS
#define OG      128           // 2*UNITS
#define OC      64            // UNITS
#define HXS     (N_NODES*UNITS)
#define INS     (N_NODES*IND)
#define KTILES  5             // ceil(132/32)
#define FQ      17            // f-quads per row (F padded 66->68)
#define CHUNKS  272           // 16*17 quads per row
#define LDSC    21            // padded fq stride in LDS
#define CAP     64            // bucket capacity per node (mean deg 8)

typedef __attribute__((ext_vector_type(8))) short bf16x8;
typedef __attribute__((ext_vector_type(4))) float f32x4;
typedef __attribute__((ext_vector_type(2))) float f32x2;
typedef unsigned long long u64;

__device__ __forceinline__ float bf2f(unsigned short u) {
  union { unsigned u; float f; } v; v.u = ((unsigned)u) << 16; return v.f;
}
__device__ __forceinline__ unsigned short f2bf(float x) {
  union { float f; unsigned u; } v; v.f = x;
  unsigned r = v.u + 0x7fffu + ((v.u >> 16) & 1u);
  return (unsigned short)(r >> 16);
}
__device__ __forceinline__ unsigned cvt2bf(float a, float b) {   // lo=bf16(a), hi=bf16(b)
  unsigned r; asm("v_cvt_pk_bf16_f32 %0, %1, %2" : "=v"(r) : "v"(a), "v"(b)); return r;
}
__device__ __forceinline__ unsigned pk4fp8(float a, float b, float c, float d) {
  int v = __builtin_amdgcn_cvt_pk_fp8_f32(a, b, 0, false);
  v = __builtin_amdgcn_cvt_pk_fp8_f32(c, d, v, true);
  return (unsigned)v;
}
__device__ __forceinline__ unsigned char f2fp8(float a) {
  return (unsigned char)(__builtin_amdgcn_cvt_pk_fp8_f32(a, 0.f, 0, false) & 0xff);
}

// ================= fused prep: pack W | fill buckets | build X8 + X0bf =================
// k-order for A/B frags: k = kt*32 + s*8 + j -> feature f = kt*16 + s*4 + (j&3),
// src = j>>2 (0=x0, 1=x1) -> original W row = 2*f + src.
__global__ __launch_bounds__(256) void prep_kernel(
    const float* __restrict__ inputs, const float* __restrict__ hx,
    const float* __restrict__ w1mu, const float* __restrict__ w1ls, const float* __restrict__ ew1,
    const float* __restrict__ b1mu, const float* __restrict__ b1ls, const float* __restrict__ eb1,
    const float* __restrict__ w2mu, const float* __restrict__ w2ls, const float* __restrict__ ew2,
    const float* __restrict__ b2mu, const float* __restrict__ b2ls, const float* __restrict__ eb2,
    const int* __restrict__ erow, const int* __restrict__ ecol, const float* __restrict__ eval,
    short* __restrict__ W1p, short* __restrict__ W2p,
    float* __restrict__ B1, float* __restrict__ B2,
    int* __restrict__ cnt, u64* __restrict__ epk,
    unsigned* __restrict__ X8, uint2* __restrict__ X0bf) {
  int blk = blockIdx.x, t = threadIdx.x;
  if (blk < 16) {                    // ---- pack W (fused reparam) ----
    int i = blk * 256 + t;
    if (i < 2560) {
      int l = i & 63, kt = (i >> 6) % KTILES, nt = i / (KTILES * 64);
      int o = nt * 16 + (l & 15), s = l >> 4;
      bf16x8 fr;
#pragma unroll
      for (int j = 0; j < 8; ++j) {
        int f = kt * 16 + s * 4 + (j & 3);
        int src = j >> 2;
        float w = 0.f;
        if (f < FDIM) { int idx = (2 * f + src) * OG + o; w = w1mu[idx] + __expf(w1ls[idx]) * ew1[idx]; }
        fr[j] = (short)f2bf(w);
      }
      *((bf16x8*)W1p + i) = fr;
    } else if (i < 3840) {
      int i2 = i - 2560;
      int l = i2 & 63, kt = (i2 >> 6) % KTILES, nt = i2 / (KTILES * 64);
      int o = nt * 16 + (l & 15), s = l >> 4;
      bf16x8 fr;
#pragma unroll
      for (int j = 0; j < 8; ++j) {
        int f = kt * 16 + s * 4 + (j & 3);
        int src = j >> 2;
        float w = 0.f;
        if (f < FDIM) { int idx = (2 * f + src) * OC + o; w = w2mu[idx] + __expf(w2ls[idx]) * ew2[idx]; }
        fr[j] = (short)f2bf(w);
      }
      *((bf16x8*)W2p + i2) = fr;
    } else if (i < 3968) {
      int j = i - 3840; B1[j] = b1mu[j] + __expf(b1ls[j]) * eb1[j];
    } else if (i < 4032) {
      int j = i - 3968; B2[j] = b2mu[j] + __expf(b2ls[j]) * eb2[j];
    }
  } else if (blk < 16 + 313) {       // ---- fill buckets ----
    int i = (blk - 16) * 256 + t;
    if (i < NEDGE) {
      int r = erow[i];
      int pos = atomicAdd(&cnt[r], 1);
      if (pos < CAP)
        epk[(size_t)r * CAP + pos] =
            (u64)(unsigned)(ecol[i] * CHUNKS) | ((u64)__float_as_uint(eval[i]) << 32);
    }
  } else {                           // ---- build X8 (fp8) + X0bf (bf16) ----
    int i = (blk - 329) * 256 + t;
    if (i >= N_NODES * CHUNKS) return;
    int n = i / CHUNKS;
    int c = i - n * CHUNKS;
    int b = c / FQ;
    int fq = c - b * FQ;
    const float* hp = hx + (size_t)b * HXS + n * UNITS;
    float v0, v1, v2, v3;
    if (fq == 0) {
      const float* ip = inputs + (size_t)b * INS + n * IND;
      v0 = ip[0]; v1 = ip[1]; v2 = hp[0]; v3 = hp[1];
    } else if (fq < 16) {
      f32x2 a = *reinterpret_cast<const f32x2*>(hp + fq * 4 - 2);
      f32x2 d = *reinterpret_cast<const f32x2*>(hp + fq * 4);
      v0 = a[0]; v1 = a[1]; v2 = d[0]; v3 = d[1];
    } else {
      f32x2 a = *reinterpret_cast<const f32x2*>(hp + 62);
      v0 = a[0]; v1 = a[1]; v2 = 0.f; v3 = 0.f;
    }
    X8[i] = pk4fp8(v0, v1, v2, v3);
    X0bf[i] = make_uint2(cvt2bf(v0, v1), cvt2bf(v2, v3));
  }
}

// ===== gather: fp8 x1 gather + Y write. Straight-line masked 8-edge head =====
// (buckets are CAP-sized and always readable; masked edges contribute exact 0.0)
__device__ __forceinline__ void gather_write(const unsigned* __restrict__ X8t,
                                             int deg, const u64* __restrict__ ebk,
                                             int t, unsigned ow0, unsigned ow1,
                                             unsigned ow0e, unsigned ow1e,
                                             unsigned short* Y) {
  const bool extra = t < 16;
  const int c = t, c2 = 256 + t;
  if (t < 48) {                       // zero LDS pads fq' 17..19
    int b = t / 3, fqp = 17 + (t - (t / 3) * 3);
    *reinterpret_cast<uint4*>(Y + (b * LDSC + fqp) * 8) = make_uint4(0u, 0u, 0u, 0u);
  }
  f32x2 g01 = {0.f, 0.f}, g23 = {0.f, 0.f}, ge01 = {0.f, 0.f}, ge23 = {0.f, 0.f};
  const unsigned* bc = X8t + c;
  const unsigned* bc2 = X8t + c2;

  // ---- head: 8 edges, fully unrolled, masked ----
  {
    unsigned o[8]; float v[8];
#pragma unroll
    for (int j = 0; j < 8; ++j) {
      u64 p = ebk[j];                      // all packet loads issue upfront
      bool on = j < deg;
      o[j] = on ? (unsigned)p : 0u;
      v[j] = on ? __uint_as_float((unsigned)(p >> 32)) : 0.f;
    }
    unsigned wv[8];
#pragma unroll
    for (int j = 0; j < 8; ++j) wv[j] = bc[o[j]];   // gathered loads back-to-back
    unsigned yv[8];
    if (extra) {
#pragma unroll
      for (int j = 0; j < 8; ++j) yv[j] = bc2[o[j]];
    }
#pragma unroll
    for (int j = 0; j < 8; ++j) {
      f32x2 vv = {v[j], v[j]};
      g01 += vv * __builtin_amdgcn_cvt_pk_f32_fp8((int)wv[j], false);
      g23 += vv * __builtin_amdgcn_cvt_pk_f32_fp8((int)wv[j], true);
      if (extra) {
        ge01 += vv * __builtin_amdgcn_cvt_pk_f32_fp8((int)yv[j], false);
        ge23 += vv * __builtin_amdgcn_cvt_pk_f32_fp8((int)yv[j], true);
      }
    }
  }
  // ---- tail: deg > 8, masked 4-wide blocks ----
  for (int e = 8; e < deg; e += 4) {
    unsigned o[4]; float v[4];
#pragma unroll
    for (int j = 0; j < 4; ++j) {
      int ee = e + j;
      u64 p = ebk[ee < CAP ? ee : CAP - 1];
      bool on = ee < deg;
      o[j] = on ? (unsigned)p : 0u;
      v[j] = on ? __uint_as_float((unsigned)(p >> 32)) : 0.f;
    }
    unsigned wv[4];
#pragma unroll
    for (int j = 0; j < 4; ++j) wv[j] = bc[o[j]];
    unsigned yv[4];
    if (extra) {
#pragma unroll
      for (int j = 0; j < 4; ++j) yv[j] = bc2[o[j]];
    }
#pragma unroll
    for (int j = 0; j < 4; ++j) {
      f32x2 vv = {v[j], v[j]};
      g01 += vv * __builtin_amdgcn_cvt_pk_f32_fp8((int)wv[j], false);
      g23 += vv * __builtin_amdgcn_cvt_pk_f32_fp8((int)wv[j], true);
      if (extra) {
        ge01 += vv * __builtin_amdgcn_cvt_pk_f32_fp8((int)yv[j], false);
        ge23 += vv * __builtin_amdgcn_cvt_pk_f32_fp8((int)yv[j], true);
      }
    }
  }

  int b = c / FQ, fq = c - (c / FQ) * FQ;
  *reinterpret_cast<uint4*>(Y + (b * LDSC + fq) * 8) =
      make_uint4(ow0, ow1, cvt2bf(g01[0], g01[1]), cvt2bf(g23[0], g23[1]));
  if (extra) {
    *reinterpret_cast<uint4*>(Y + (15 * LDSC + (t + 1)) * 8) =
        make_uint4(ow0e, ow1e, cvt2bf(ge01[0], ge01[1]), cvt2bf(ge23[0], ge23[1]));
  }
}

// A-frag: lane (ml,s) kt reads 16B = (x0[f0..f0+3], x1[f0..f0+3]), f0 = kt*16+s*4
__device__ __forceinline__ void build_afrag(const unsigned short* Y, int ml, int s, bf16x8* af) {
#pragma unroll
  for (int kt = 0; kt < KTILES; ++kt)
    af[kt] = *reinterpret_cast<const bf16x8*>(Y + (ml * LDSC + kt * 4 + s) * 8);
}

// ------- gates: own row from X0bf (bf16); gconv1 (MFMA) + sigmoid;
//         r*h -> X8c (fp8, LDS-staged), {u,u*h} -> upk.  2 barriers total. -------
__global__ __launch_bounds__(256, 8) void gates_kernel(
    const uint2* __restrict__ X0bf, const unsigned* __restrict__ X8,
    const short* __restrict__ W1p, const float* __restrict__ B1,
    const int* __restrict__ cnt, const u64* __restrict__ epk,
    unsigned* __restrict__ X8c, unsigned* __restrict__ upk) {
  __shared__ __align__(16) unsigned short Y[16 * LDSC * 8];
  __shared__ __align__(16) unsigned X8s[CHUNKS];
  int n = blockIdx.x, t = threadIdx.x;
  int lane = t & 63, w = t >> 6;

  // own row: one coalesced 8B bf16 load
  const uint2* xrow = X0bf + (size_t)n * CHUNKS;
  uint2 own = xrow[t];
  unsigned ow0 = own.x, ow1 = own.y;
  int b0 = t / FQ, fq0 = t - b0 * FQ;
  X8s[t] = (fq0 == 0)
      ? pk4fp8(bf2f((unsigned short)(ow0 & 0xffffu)), bf2f((unsigned short)(ow0 >> 16)), 0.f, 0.f)
      : 0u;
  unsigned ow0e = 0, ow1e = 0;
  if (t < 16) {
    uint2 own2 = xrow[256 + t];
    ow0e = own2.x; ow1e = own2.y;
    X8s[256 + t] = 0u;               // fq = t+1 != 0
  }

  int deg = cnt[n]; if (deg > CAP) deg = CAP;
  gather_write(X8, deg, epk + (size_t)n * CAP, t, ow0, ow1, ow0e, ow1e, Y);
  __syncthreads();                   // Y + X8s init complete

  int ml = lane & 15, s = lane >> 4;
  bf16x8 af[KTILES];
  build_afrag(Y, ml, s, af);

  const bf16x8* Wp = (const bf16x8*)W1p;
#pragma unroll
  for (int q = 0; q < 2; ++q) {
    int nt = w * 2 + q;
    f32x4 acc = {0.f, 0.f, 0.f, 0.f};
#pragma unroll
    for (int kt = 0; kt < KTILES; ++kt)
      acc = __builtin_amdgcn_mfma_f32_16x16x32_bf16(af[kt], Wp[(nt * KTILES + kt) * 64 + lane],
                                                    acc, 0, 0, 0);
    int o = nt * 16 + ml;           // output col; rows = batch s*4+r
    float bias = B1[o];
    int f = (o < UNITS ? o : o - UNITS) + IND, fqi = f >> 2, fr = f & 3;
    if (o < UNITS) {
#pragma unroll
      for (int r = 0; r < 4; ++r) {
        int b = s * 4 + r;
        float h = bf2f(Y[(b * LDSC + fqi) * 8 + fr]);   // h (bf16) from staged own-row x0 quad
        float sg = 1.f / (1.f + __expf(-(acc[r] + bias)));
        ((unsigned char*)X8s)[(b * FQ + fqi) * 4 + fr] = f2fp8(sg * h);
      }
    } else {
      int ou = o - UNITS;
#pragma unroll
      for (int r = 0; r < 4; ++r) {
        int b = s * 4 + r;
        float h = bf2f(Y[(b * LDSC + fqi) * 8 + fr]);
        float u = 1.f / (1.f + __expf(-(acc[r] + bias)));
        upk[(size_t)b * HXS + n * UNITS + ou] = cvt2bf(u, u * h);
      }
    }
  }
  __syncthreads();                   // X8s bytes complete
  // coalesced fp8 row store
  X8c[(size_t)n * CHUNKS + t] = X8s[t];
  if (t < 16) X8c[(size_t)n * CHUNKS + 256 + t] = X8s[256 + t];
}

// ------- candidate: gconv2 (MFMA) + tanh + GRU combine. 1 barrier total. -------
__global__ __launch_bounds__(256, 8) void cand_kernel(
    const unsigned* __restrict__ X8c, const short* __restrict__ W2p,
    const float* __restrict__ B2,
    const int* __restrict__ cnt, const u64* __restrict__ epk,
    const unsigned* __restrict__ upk, float* __restrict__ out) {
  __shared__ __align__(16) unsigned short Y[16 * LDSC * 8];
  int n = blockIdx.x, t = threadIdx.x;
  int lane = t & 63, w = t >> 6;

  // own row from fp8 table
  const unsigned* xrow = X8c + (size_t)n * CHUNKS;
  unsigned wo = xrow[t];
  f32x2 lo = __builtin_amdgcn_cvt_pk_f32_fp8((int)wo, false);
  f32x2 hi = __builtin_amdgcn_cvt_pk_f32_fp8((int)wo, true);
  unsigned ow0 = cvt2bf(lo[0], lo[1]), ow1 = cvt2bf(hi[0], hi[1]);
  unsigned ow0e = 0, ow1e = 0;
  if (t < 16) {
    unsigned wo2 = xrow[256 + t];
    f32x2 lo2 = __builtin_amdgcn_cvt_pk_f32_fp8((int)wo2, false);
    f32x2 hi2 = __builtin_amdgcn_cvt_pk_f32_fp8((int)wo2, true);
    ow0e = cvt2bf(lo2[0], lo2[1]); ow1e = cvt2bf(hi2[0], hi2[1]);
  }

  int deg = cnt[n]; if (deg > CAP) deg = CAP;
  gather_write(X8c, deg, epk + (size_t)n * CAP, t, ow0, ow1, ow0e, ow1e, Y);
  __syncthreads();

  int ml = lane & 15, s = lane >> 4;
  bf16x8 af[KTILES];
  build_afrag(Y, ml, s, af);

  const bf16x8* Wp = (const bf16x8*)W2p;
  f32x4 acc = {0.f, 0.f, 0.f, 0.f};
#pragma unroll
  for (int kt = 0; kt < KTILES; ++kt)
    acc = __builtin_amdgcn_mfma_f32_16x16x32_bf16(af[kt], Wp[(w * KTILES + kt) * 64 + lane],
                                                  acc, 0, 0, 0);
  int o = w * 16 + ml;
  float bias = B2[o];
#pragma unroll
  for (int r = 0; r < 4; ++r) {
    int b = s * 4 + r;
    size_t idx = (size_t)b * HXS + n * UNITS + o;
    float x = acc[r] + bias;
    float c = 1.f - 2.f / (__expf(2.f * x) + 1.f);   // tanh
    unsigned pk = upk[idx];
    float u = bf2f((unsigned short)(pk & 0xffffu));
    float uh = bf2f((unsigned short)(pk >> 16));
    out[idx] = uh + (1.f - u) * c;
  }
}

extern "C" void kernel_launch(void* const* d_in, const int* in_sizes, int n_in,
                              void* d_out, int out_size, void* d_ws, size_t ws_size,
                              hipStream_t stream) {
  const float* inputs = (const float*)d_in[0];
  const float* hx     = (const float*)d_in[1];
  const float* eval   = (const float*)d_in[2];
  const float* w1mu   = (const float*)d_in[3];
  const float* w1ls   = (const float*)d_in[4];
  const float* b1mu   = (const float*)d_in[5];
  const float* b1ls   = (const float*)d_in[6];
  const float* w2mu   = (const float*)d_in[7];
  const float* w2ls   = (const float*)d_in[8];
  const float* b2mu   = (const float*)d_in[9];
  const float* b2ls   = (const float*)d_in[10];
  const float* ew1    = (const float*)d_in[11];
  const float* eb1    = (const float*)d_in[12];
  const float* ew2    = (const float*)d_in[13];
  const float* eb2    = (const float*)d_in[14];
  const int* erow     = (const int*)d_in[15];
  const int* ecol     = (const int*)d_in[16];
  float* out = (float*)d_out;

  char* p = (char*)d_ws;
  short* W1p = (short*)p;                   p += 20480 * 2;
  short* W2p = (short*)p;                   p += 10240 * 2;
  float* B1  = (float*)p;                   p += 128 * 4;
  float* B2  = (float*)p;                   p += 64 * 4;
  unsigned* X8  = (unsigned*)p;             p += (size_t)N_NODES * CHUNKS * 4;
  unsigned* X8c = (unsigned*)p;             p += (size_t)N_NODES * CHUNKS * 4;
  uint2* X0bf = (uint2*)p;                  p += (size_t)N_NODES * CHUNKS * 8;
  unsigned* upk = (unsigned*)p;             p += (size_t)BATCH * HXS * 4;
  int* cnt    = (int*)p;                    p += N_NODES * 4;
  u64* epk    = (u64*)p;                    p += (size_t)N_NODES * CAP * 8;

  hipMemsetAsync(cnt, 0, N_NODES * sizeof(int), stream);
  prep_kernel<<<16 + 313 + (N_NODES * CHUNKS) / 256, 256, 0, stream>>>(
      inputs, hx, w1mu, w1ls, ew1, b1mu, b1ls, eb1,
      w2mu, w2ls, ew2, b2mu, b2ls, eb2, erow, ecol, eval,
      W1p, W2p, B1, B2, cnt, epk, X8, X0bf);
  gates_kernel<<<N_NODES, 256, 0, stream>>>(X0bf, X8, W1p, B1, cnt, epk, X8c, upk);
  cand_kernel<<<N_NODES, 256, 0, stream>>>(X8c, W2p, B2, cnt, epk, upk, out);
}